// Round 17
// baseline (543.592 us; speedup 1.0000x reference)
//
#include <hip/hip_runtime.h>
#include <hip/hip_bf16.h>

#define NNODES 200000
#define NEDGES 6400000
#define NFEAT  128
#define NH     16
#define NMLP   100
#define NCLS   27
#define NGRAPH 4096

#define BKTSH  10                      // bucket = dst >> 10  (1024 nodes/bucket)
#define BKTW   1024
#define NBKT   ((NNODES + BKTW - 1) / BKTW)   // 196
#define NBLKA  512                     // phase-A blocks (1024 threads, 2/CU)
#define ABLK   1024
#define EPB    (NEDGES / NBLKA)        // 12500 edges per phase-A block
#define EPB4   (EPB / 4)               // 3125 int4 per block
#define HSZ    (NBKT * NBLKA)          // 100352 histogram entries
#define SCANB  1024
#define NSCAN2 ((HSZ + SCANB - 1) / SCANB)   // 98
#define CAP    34816                   // LDS out-buffer entries (136 KB)

#define SPLIT  100000                  // src-half split: slice = 3.2 MB bf16
#define GBLK   1792                    // gather blocks (7/CU -> co-resident)
#define NPB    112                     // nodes per gather block (1792*112 >= N)
#define SPINMAX 2000

typedef int v4i __attribute__((ext_vector_type(4)));

__device__ __forceinline__ unsigned short f2bf(float f) {
    unsigned u = __float_as_uint(f);
    return (unsigned short)((u + 0x7FFF + ((u >> 16) & 1)) >> 16);   // RNE
}
__device__ __forceinline__ float bf2f(unsigned short s) {
    return __uint_as_float(((unsigned)s) << 16);
}

// ---------------------------------------------------------------------------
// Phase A1: per-block LDS histogram over coarse buckets (dst>>10) -> H[b][k]
__global__ __launch_bounds__(ABLK) void k_histA(const int* __restrict__ dst,
                                                int* __restrict__ H) {
    __shared__ int hist[NBKT];
    int tid = threadIdx.x, k = blockIdx.x;
    for (int b = tid; b < NBKT; b += ABLK) hist[b] = 0;
    __syncthreads();
    const v4i* d4 = (const v4i*)(dst + (size_t)k * EPB);
    #pragma unroll 2
    for (int q = tid; q < EPB4; q += ABLK) {
        v4i d = __builtin_nontemporal_load(d4 + q);
        atomicAdd(&hist[d.x >> BKTSH], 1);
        atomicAdd(&hist[d.y >> BKTSH], 1);
        atomicAdd(&hist[d.z >> BKTSH], 1);
        atomicAdd(&hist[d.w >> BKTSH], 1);
    }
    __syncthreads();
    for (int b = tid; b < NBKT; b += ABLK) H[b * NBLKA + k] = hist[b];
}

// 3-kernel exclusive scan over H (HSZ elements), in place
__global__ __launch_bounds__(256) void k_scan_part(const int* __restrict__ A,
                                                   int* __restrict__ bsum) {
    __shared__ int sd[256];
    int tid = threadIdx.x;
    int i0 = blockIdx.x * SCANB + tid * 4;
    int s = 0;
    #pragma unroll
    for (int u = 0; u < 4; ++u) {
        int i = i0 + u;
        if (i < HSZ) s += A[i];
    }
    sd[tid] = s;
    __syncthreads();
    for (int off = 128; off > 0; off >>= 1) {
        if (tid < off) sd[tid] += sd[tid + off];
        __syncthreads();
    }
    if (tid == 0) bsum[blockIdx.x] = sd[0];
}

// single-block exclusive scan of block sums; zeroes G, colidx pad, barrier ctrs
__global__ __launch_bounds__(256) void k_scan_top(int* __restrict__ bsum,
                                                  float* __restrict__ G,
                                                  int* __restrict__ cipad,
                                                  int* __restrict__ bars) {
    float4* G4 = (float4*)G;
    int tid = threadIdx.x;
    #pragma unroll
    for (int t = 0; t < (NGRAPH * NH / 4) / 256; ++t)
        G4[tid + t * 256] = make_float4(0.f, 0.f, 0.f, 0.f);
    if (tid < 64) cipad[tid] = 0;
    if (tid < 2)  bars[tid] = 0;

    __shared__ int sd[256];
    int i0 = tid * 4;
    int c[4];
    #pragma unroll
    for (int u = 0; u < 4; ++u) {
        int i = i0 + u;
        c[u] = (i < NSCAN2) ? bsum[i] : 0;
    }
    int mysum = c[0] + c[1] + c[2] + c[3];
    sd[tid] = mysum;
    __syncthreads();
    for (int off = 1; off < 256; off <<= 1) {
        int v = (tid >= off) ? sd[tid - off] : 0;
        __syncthreads();
        sd[tid] += v;
        __syncthreads();
    }
    int base = sd[tid] - mysum;
    #pragma unroll
    for (int u = 0; u < 4; ++u) {
        int i = i0 + u;
        if (i < NSCAN2) { bsum[i] = base; base += c[u]; }
    }
}

__global__ __launch_bounds__(256) void k_scan_final(int* __restrict__ A,
                                                    const int* __restrict__ bsum) {
    __shared__ int sd[256];
    int tid = threadIdx.x;
    int i0 = blockIdx.x * SCANB + tid * 4;
    int c[4];
    #pragma unroll
    for (int u = 0; u < 4; ++u) {
        int i = i0 + u;
        c[u] = (i < HSZ) ? A[i] : 0;
    }
    int mysum = c[0] + c[1] + c[2] + c[3];
    sd[tid] = mysum;
    __syncthreads();
    for (int off = 1; off < 256; off <<= 1) {
        int v = (tid >= off) ? sd[tid - off] : 0;
        __syncthreads();
        sd[tid] += v;
        __syncthreads();
    }
    int base = bsum[blockIdx.x] + sd[tid] - mysum;
    #pragma unroll
    for (int u = 0; u < 4; ++u) {
        int i = i0 + u;
        if (i < HSZ) { A[i] = base; base += c[u]; }
    }
}

// Phase A2: scatter edges into bucket-grouped array P (packed (dst&1023)<<18|src)
__global__ __launch_bounds__(ABLK) void k_scatterA(const int* __restrict__ src,
                                                   const int* __restrict__ dst,
                                                   const int* __restrict__ S,
                                                   int* __restrict__ P) {
    __shared__ int cnt[NBKT];
    int tid = threadIdx.x, k = blockIdx.x;
    for (int b = tid; b < NBKT; b += ABLK) cnt[b] = S[b * NBLKA + k];
    __syncthreads();
    const v4i* d4 = (const v4i*)(dst + (size_t)k * EPB);
    const v4i* s4 = (const v4i*)(src + (size_t)k * EPB);
    #pragma unroll 2
    for (int q = tid; q < EPB4; q += ABLK) {
        v4i d = __builtin_nontemporal_load(d4 + q);
        v4i s = __builtin_nontemporal_load(s4 + q);
        int p0 = atomicAdd(&cnt[d.x >> BKTSH], 1);
        int p1 = atomicAdd(&cnt[d.y >> BKTSH], 1);
        int p2 = atomicAdd(&cnt[d.z >> BKTSH], 1);
        int p3 = atomicAdd(&cnt[d.w >> BKTSH], 1);
        P[p0] = ((d.x & (BKTW - 1)) << 18) | s.x;
        P[p1] = ((d.y & (BKTW - 1)) << 18) | s.y;
        P[p2] = ((d.z & (BKTW - 1)) << 18) | s.z;
        P[p3] = ((d.w & (BKTW - 1)) << 18) | s.w;
    }
}

// Phase B: one block (1024 thr) per bucket -> rp2[(node,half)], dinv, colidx.
// colidx sub-sorted by (node, src-half); built in LDS, streamed out coalesced.
__global__ __launch_bounds__(ABLK) void k_csrB(const int* __restrict__ P,
                                               const int* __restrict__ S,
                                               int* __restrict__ rp2,
                                               float* __restrict__ dinv,
                                               int* __restrict__ colidx) {
    __shared__ int outl[CAP];          // 136 KB
    __shared__ int deg2[BKTW * 2];     // 8 KB
    __shared__ int wp2[BKTW * 2];      // 8 KB
    __shared__ int sc[BKTW];           // 4 KB
    __shared__ int se[2];
    int b = blockIdx.x, tid = threadIdx.x;
    if (tid == 0) {
        se[0] = S[b * NBLKA];
        se[1] = (b == NBKT - 1) ? NEDGES : S[(b + 1) * NBLKA];
    }
    deg2[tid] = 0;
    deg2[tid + BKTW] = 0;
    __syncthreads();
    int start = se[0], end = se[1];

    for (int i = start + tid; i < end; i += ABLK) {
        int v = P[i];
        atomicAdd(&deg2[(v >> 18) * 2 + ((v & 0x3FFFF) >= SPLIT)], 1);
    }
    __syncthreads();

    int c0 = deg2[tid * 2], c1 = deg2[tid * 2 + 1];
    int mysum = c0 + c1;
    sc[tid] = mysum;
    __syncthreads();
    for (int off = 1; off < BKTW; off <<= 1) {
        int v = (tid >= off) ? sc[tid - off] : 0;
        __syncthreads();
        sc[tid] += v;
        __syncthreads();
    }
    int p0 = start + sc[tid] - mysum;   // exclusive prefix (absolute)
    int p1 = p0 + c0;
    wp2[tid * 2] = p0;
    wp2[tid * 2 + 1] = p1;
    int node = b * BKTW + tid;
    if (node < NNODES) {
        rp2[(size_t)node * 2]     = p0;
        rp2[(size_t)node * 2 + 1] = p1;
        dinv[node] = rsqrtf(1.f + (float)mysum);
    }
    if (b == 0 && tid == 0) rp2[2 * NNODES] = NEDGES;
    __syncthreads();

    for (int i = start + tid; i < end; i += ABLK) {
        int v = P[i];
        int s = v & 0x3FFFF;
        int pos = atomicAdd(&wp2[(v >> 18) * 2 + (s >= SPLIT)], 1);
        int rel = pos - start;
        if (rel < CAP) outl[rel] = s;
        else           colidx[pos] = s;
    }
    __syncthreads();

    int cnt = end - start;
    if (cnt > CAP) cnt = CAP;
    for (int i = tid; i < cnt; i += ABLK)
        colidx[start + i] = outl[i];
}

// A1b[i][j] = bf16( dinv[i] * (x[i] @ W1)[j] )   (node-major, 32B rows)
#define GROWS 64
#define GPAD  129
__global__ __launch_bounds__(256) void k_gemm1(const float* __restrict__ x,
                                               const float* __restrict__ W1,
                                               const float* __restrict__ dinv,
                                               unsigned short* __restrict__ A1b) {
    __shared__ float xt[GROWS * GPAD];       // 33 KB
    __shared__ float Ws[NFEAT * NH];         // 8 KB
    int tid = threadIdx.x;
    int r0 = blockIdx.x * GROWS;

    #pragma unroll
    for (int t = 0; t < (NFEAT * NH) / 256; ++t)   // 8
        Ws[tid + t * 256] = W1[tid + t * 256];

    const float4* xg = (const float4*)(x + (size_t)r0 * NFEAT);
    #pragma unroll
    for (int t = 0; t < (GROWS * NFEAT / 4) / 256; ++t) {  // 8
        int fi = tid + t * 256;              // float4 index within tile
        float4 v = xg[fi];
        int row = fi >> 5;                   // 32 float4 per row
        int c4  = fi & 31;
        float* p = &xt[row * GPAD + c4 * 4];
        p[0] = v.x; p[1] = v.y; p[2] = v.z; p[3] = v.w;
    }
    __syncthreads();

    int r  = tid >> 2;      // 0..63
    int jq = tid & 3;       // output col quarter
    float4 acc = make_float4(0.f, 0.f, 0.f, 0.f);
    #pragma unroll 8
    for (int k = 0; k < NFEAT; ++k) {
        float xv = xt[r * GPAD + k];
        float4 w = *(const float4*)&Ws[k * NH + jq * 4];
        acc.x += xv * w.x; acc.y += xv * w.y;
        acc.z += xv * w.z; acc.w += xv * w.w;
    }
    int n = r0 + r;
    float s = dinv[n];
    ushort4 o;
    o.x = f2bf(acc.x * s); o.y = f2bf(acc.y * s);
    o.z = f2bf(acc.z * s); o.w = f2bf(acc.w * s);
    *(ushort4*)&A1b[(size_t)n * NH + jq * 4] = o;
}

// Register-resident 2-phase sliced gather body (shared by both layers).
// acc[r] accumulates node base+r*16+nl over both src-slices; best-effort
// global barrier between phases keeps all XCDs on the same 3.2 MB slice.
__device__ __forceinline__ void gather_phases(const unsigned short* __restrict__ Ab,
                                              const int* __restrict__ rp2,
                                              const int* __restrict__ ci,
                                              int* __restrict__ bar,
                                              int base, int nl, int j,
                                              float acc[7]) {
    #pragma unroll
    for (int p = 0; p < 2; ++p) {
        for (int r = 0; r < 7; ++r) {
            int n = base + r * 16 + nl;
            if (n >= NNODES) continue;
            int k = rp2[(size_t)n * 2 + p];
            int e = rp2[(size_t)n * 2 + p + 1];
            if (p == (int)(n >= SPLIT))          // self row lives in this slice
                acc[r] += bf2f(Ab[(size_t)n * NH + j]);
            for (; k + 8 <= e; k += 8) {
                int   c[8];
                float v[8];
                #pragma unroll
                for (int u = 0; u < 8; ++u) c[u] = ci[k + u];
                #pragma unroll
                for (int u = 0; u < 8; ++u) v[u] = bf2f(Ab[(size_t)c[u] * NH + j]);
                #pragma unroll
                for (int u = 0; u < 8; ++u) acc[r] += v[u];
            }
            if (k < e) {
                int   c[8];
                float v[8];
                #pragma unroll
                for (int u = 0; u < 8; ++u) c[u] = ci[k + u];   // pad-protected
                #pragma unroll
                for (int u = 0; u < 8; ++u) v[u] = bf2f(Ab[(size_t)c[u] * NH + j]);
                #pragma unroll
                for (int u = 0; u < 8; ++u) acc[r] += (k + u < e) ? v[u] : 0.f;
            }
        }
        if (p == 0) {                            // best-effort grid barrier
            __syncthreads();
            if (threadIdx.x == 0) {
                atomicAdd(bar, 1);
                int t = 0;
                while (__hip_atomic_load(bar, __ATOMIC_RELAXED,
                                         __HIP_MEMORY_SCOPE_AGENT) < GBLK
                       && t < SPINMAX) {
                    __builtin_amdgcn_s_sleep(16);
                    ++t;
                }
            }
            __syncthreads();
        }
    }
}

// gather layer 1: + relu/bias + h@W2 epilogue -> A2b
__global__ __launch_bounds__(256, 8) void k_gatherR1(const unsigned short* __restrict__ A1b,
                                                     const int* __restrict__ rp2,
                                                     const int* __restrict__ ci,
                                                     const float* __restrict__ dinv,
                                                     const float* __restrict__ b1,
                                                     const float* __restrict__ W2,
                                                     unsigned short* __restrict__ A2b,
                                                     int* __restrict__ bar) {
    __shared__ float W2s[NH * NH];
    __shared__ float b1s[NH];
    int tid = threadIdx.x;
    if (tid < NH * NH) W2s[tid] = W2[tid];
    if (tid < NH)      b1s[tid] = b1[tid];
    __syncthreads();

    int nl = tid >> 4, j = tid & 15;
    int base = blockIdx.x * NPB;
    float acc[7];
    #pragma unroll
    for (int r = 0; r < 7; ++r) acc[r] = 0.f;

    gather_phases(A1b, rp2, ci, bar, base, nl, j, acc);

    #pragma unroll
    for (int r = 0; r < 7; ++r) {
        int n = base + r * 16 + nl;
        if (n >= NNODES) continue;
        float dv = dinv[n];
        float h = fmaxf(acc[r] * dv + b1s[j], 0.f);
        float o = 0.f;
        #pragma unroll
        for (int kk = 0; kk < NH; ++kk)
            o += __shfl(h, kk, 16) * W2s[kk * NH + j];
        __builtin_nontemporal_store(f2bf(o * dv), &A2b[(size_t)n * NH + j]);
    }
}

// gather layer 2: + bias + pool epilogue -> G
__global__ __launch_bounds__(256, 8) void k_gatherR2(const unsigned short* __restrict__ A2b,
                                                     const int* __restrict__ rp2,
                                                     const int* __restrict__ ci,
                                                     const float* __restrict__ dinv,
                                                     const float* __restrict__ b2,
                                                     const int* __restrict__ batch,
                                                     float* __restrict__ G,
                                                     int* __restrict__ bar) {
    __shared__ float b2s[NH];
    int tid = threadIdx.x;
    if (tid < NH) b2s[tid] = b2[tid];
    __syncthreads();

    int nl = tid >> 4, j = tid & 15;
    int base = blockIdx.x * NPB;
    float acc[7];
    #pragma unroll
    for (int r = 0; r < 7; ++r) acc[r] = 0.f;

    gather_phases(A2b, rp2, ci, bar, base, nl, j, acc);

    #pragma unroll
    for (int r = 0; r < 7; ++r) {
        int n = base + r * 16 + nl;
        if (n >= NNODES) continue;
        float h2 = acc[r] * dinv[n] + b2s[j];
        atomicAdd(&G[(size_t)batch[n] * NH + j], h2);
    }
}

// head: per graph: relu(G) -> MLP1 -> relu -> MLP2 -> out
__global__ __launch_bounds__(128) void k_head(const float* __restrict__ G,
                                              const float* __restrict__ Wl1,
                                              const float* __restrict__ bl1,
                                              const float* __restrict__ Wl2,
                                              const float* __restrict__ bl2,
                                              float* __restrict__ out) {
    __shared__ float gv[NH];
    __shared__ float g1[NMLP];
    int g = blockIdx.x, tid = threadIdx.x;

    if (tid < NH) gv[tid] = fmaxf(G[(size_t)g * NH + tid], 0.f);
    __syncthreads();

    if (tid < NMLP) {
        float a = bl1[tid];
        #pragma unroll
        for (int k = 0; k < NH; ++k) a += gv[k] * Wl1[k * NMLP + tid];
        g1[tid] = fmaxf(a, 0.f);
    }
    __syncthreads();

    if (tid < NCLS) {
        float a = bl2[tid];
        for (int k = 0; k < NMLP; ++k) a += g1[k] * Wl2[k * NCLS + tid];
        out[(size_t)g * NCLS + tid] = a;
    }
}

// ---------------------------------------------------------------------------
extern "C" void kernel_launch(void* const* d_in, const int* in_sizes, int n_in,
                              void* d_out, int out_size, void* d_ws, size_t ws_size,
                              hipStream_t stream) {
    const float* x     = (const float*)d_in[0];
    const int*   edge  = (const int*)d_in[1];   // [2, E] flat: src then dst
    const int*   batch = (const int*)d_in[2];
    const float* W1    = (const float*)d_in[3];
    const float* b1    = (const float*)d_in[4];
    const float* W2    = (const float*)d_in[5];
    const float* b2    = (const float*)d_in[6];
    const float* Wl1   = (const float*)d_in[7];
    const float* bl1   = (const float*)d_in[8];
    const float* Wl2   = (const float*)d_in[9];
    const float* bl2   = (const float*)d_in[10];
    float*       out   = (float*)d_out;

    // workspace layout (256B aligned)
    char* ws = (char*)d_ws;
    size_t cur = 0;
    auto alloc = [&](size_t bytes) {
        void* p = ws + cur;
        cur += (bytes + 255) & ~(size_t)255;
        return p;
    };
    int*   H      = (int*)  alloc((size_t)HSZ * 4);            // 401 KB (becomes S)
    int*   bsum   = (int*)  alloc((size_t)NSCAN2 * 4);
    int*   P      = (int*)  alloc((size_t)NEDGES * 4);         // 25.6 MB packed pairs
    int*   colidx = (int*)  alloc((size_t)(NEDGES + 64) * 4);  // + 64-int zero pad
    int*   rp2    = (int*)  alloc((size_t)(2 * NNODES + 2) * 4);
    float* dinv   = (float*)alloc((size_t)NNODES * 4);
    float* G      = (float*)alloc((size_t)NGRAPH * NH * 4);
    int*   bars   = (int*)  alloc(2 * 4);
    // bf16 tables alias P (dead after k_csrB): 2 x 6.4 MB
    unsigned short* A1b = (unsigned short*)P;
    unsigned short* A2b = A1b + (size_t)NNODES * NH;

    const int* src = edge;
    const int* dst = edge + NEDGES;

    int nb_gemm = NNODES / GROWS;                     // 3125

    k_histA     <<<NBLKA,  ABLK, 0, stream>>>(dst, H);
    k_scan_part <<<NSCAN2, 256, 0, stream>>>(H, bsum);
    k_scan_top  <<<1,      256, 0, stream>>>(bsum, G, colidx + NEDGES, bars);
    k_scan_final<<<NSCAN2, 256, 0, stream>>>(H, bsum);
    k_scatterA  <<<NBLKA,  ABLK, 0, stream>>>(src, dst, H, P);
    k_csrB      <<<NBKT,   ABLK, 0, stream>>>(P, H, rp2, dinv, colidx);
    k_gemm1     <<<nb_gemm, 256, 0, stream>>>(x, W1, dinv, A1b);
    k_gatherR1  <<<GBLK,   256, 0, stream>>>(A1b, rp2, colidx, dinv, b1, W2, A2b, bars + 0);
    k_gatherR2  <<<GBLK,   256, 0, stream>>>(A2b, rp2, colidx, dinv, b2, batch, G, bars + 1);
    k_head      <<<NGRAPH, 128, 0, stream>>>(G, Wl1, bl1, Wl2, bl2, out);
}

// Round 18
// 285.552 us; speedup vs baseline: 1.9037x; 1.9037x over previous
//
#include <hip/hip_runtime.h>
#include <hip/hip_bf16.h>

#define NNODES 200000
#define NEDGES 6400000
#define NFEAT  128
#define NH     16
#define NMLP   100
#define NCLS   27
#define NGRAPH 4096

#define BKTSH  10                      // bucket = dst >> 10  (1024 nodes/bucket)
#define BKTW   1024
#define NBKT   ((NNODES + BKTW - 1) / BKTW)   // 196
#define NBLKA  512                     // phase-A blocks (1024 threads, 2/CU)
#define ABLK   1024
#define EPB    (NEDGES / NBLKA)        // 12500 edges per phase-A block
#define EPB4   (EPB / 4)               // 3125 int4 per block
#define HSZ    (NBKT * NBLKA)          // 100352 histogram entries
#define SCANB  1024
#define NSCAN2 ((HSZ + SCANB - 1) / SCANB)   // 98
#define CAP    34816                   // LDS out-buffer entries (136 KB)

typedef int v4i __attribute__((ext_vector_type(4)));

__device__ __forceinline__ unsigned short f2bf(float f) {
    unsigned u = __float_as_uint(f);
    return (unsigned short)((u + 0x7FFF + ((u >> 16) & 1)) >> 16);   // RNE
}
__device__ __forceinline__ float bf2f(unsigned short s) {
    return __uint_as_float(((unsigned)s) << 16);
}

// ---------------------------------------------------------------------------
// Phase A1: per-block LDS histogram over coarse buckets (dst>>10) -> H[b][k]
__global__ __launch_bounds__(ABLK) void k_histA(const int* __restrict__ dst,
                                                int* __restrict__ H) {
    __shared__ int hist[NBKT];
    int tid = threadIdx.x, k = blockIdx.x;
    for (int b = tid; b < NBKT; b += ABLK) hist[b] = 0;
    __syncthreads();
    const v4i* d4 = (const v4i*)(dst + (size_t)k * EPB);
    #pragma unroll 2
    for (int q = tid; q < EPB4; q += ABLK) {
        v4i d = __builtin_nontemporal_load(d4 + q);
        atomicAdd(&hist[d.x >> BKTSH], 1);
        atomicAdd(&hist[d.y >> BKTSH], 1);
        atomicAdd(&hist[d.z >> BKTSH], 1);
        atomicAdd(&hist[d.w >> BKTSH], 1);
    }
    __syncthreads();
    for (int b = tid; b < NBKT; b += ABLK) H[b * NBLKA + k] = hist[b];
}

// 3-kernel exclusive scan over H (HSZ elements), in place
__global__ __launch_bounds__(256) void k_scan_part(const int* __restrict__ A,
                                                   int* __restrict__ bsum) {
    __shared__ int sd[256];
    int tid = threadIdx.x;
    int i0 = blockIdx.x * SCANB + tid * 4;
    int s = 0;
    #pragma unroll
    for (int u = 0; u < 4; ++u) {
        int i = i0 + u;
        if (i < HSZ) s += A[i];
    }
    sd[tid] = s;
    __syncthreads();
    for (int off = 128; off > 0; off >>= 1) {
        if (tid < off) sd[tid] += sd[tid + off];
        __syncthreads();
    }
    if (tid == 0) bsum[blockIdx.x] = sd[0];
}

// single-block exclusive scan of block sums; zeroes G and the colidx pad
__global__ __launch_bounds__(256) void k_scan_top(int* __restrict__ bsum,
                                                  float* __restrict__ G,
                                                  int* __restrict__ cipad) {
    float4* G4 = (float4*)G;
    int tid = threadIdx.x;
    #pragma unroll
    for (int t = 0; t < (NGRAPH * NH / 4) / 256; ++t)
        G4[tid + t * 256] = make_float4(0.f, 0.f, 0.f, 0.f);
    if (tid < 64) cipad[tid] = 0;

    __shared__ int sd[256];
    int i0 = tid * 4;
    int c[4];
    #pragma unroll
    for (int u = 0; u < 4; ++u) {
        int i = i0 + u;
        c[u] = (i < NSCAN2) ? bsum[i] : 0;
    }
    int mysum = c[0] + c[1] + c[2] + c[3];
    sd[tid] = mysum;
    __syncthreads();
    for (int off = 1; off < 256; off <<= 1) {
        int v = (tid >= off) ? sd[tid - off] : 0;
        __syncthreads();
        sd[tid] += v;
        __syncthreads();
    }
    int base = sd[tid] - mysum;
    #pragma unroll
    for (int u = 0; u < 4; ++u) {
        int i = i0 + u;
        if (i < NSCAN2) { bsum[i] = base; base += c[u]; }
    }
}

__global__ __launch_bounds__(256) void k_scan_final(int* __restrict__ A,
                                                    const int* __restrict__ bsum) {
    __shared__ int sd[256];
    int tid = threadIdx.x;
    int i0 = blockIdx.x * SCANB + tid * 4;
    int c[4];
    #pragma unroll
    for (int u = 0; u < 4; ++u) {
        int i = i0 + u;
        c[u] = (i < HSZ) ? A[i] : 0;
    }
    int mysum = c[0] + c[1] + c[2] + c[3];
    sd[tid] = mysum;
    __syncthreads();
    for (int off = 1; off < 256; off <<= 1) {
        int v = (tid >= off) ? sd[tid - off] : 0;
        __syncthreads();
        sd[tid] += v;
        __syncthreads();
    }
    int base = bsum[blockIdx.x] + sd[tid] - mysum;
    #pragma unroll
    for (int u = 0; u < 4; ++u) {
        int i = i0 + u;
        if (i < HSZ) { A[i] = base; base += c[u]; }
    }
}

// Phase A2: scatter edges into bucket-grouped array P (packed (dst&1023)<<18|src)
__global__ __launch_bounds__(ABLK) void k_scatterA(const int* __restrict__ src,
                                                   const int* __restrict__ dst,
                                                   const int* __restrict__ S,
                                                   int* __restrict__ P) {
    __shared__ int cnt[NBKT];
    int tid = threadIdx.x, k = blockIdx.x;
    for (int b = tid; b < NBKT; b += ABLK) cnt[b] = S[b * NBLKA + k];
    __syncthreads();
    const v4i* d4 = (const v4i*)(dst + (size_t)k * EPB);
    const v4i* s4 = (const v4i*)(src + (size_t)k * EPB);
    #pragma unroll 2
    for (int q = tid; q < EPB4; q += ABLK) {
        v4i d = __builtin_nontemporal_load(d4 + q);
        v4i s = __builtin_nontemporal_load(s4 + q);
        int p0 = atomicAdd(&cnt[d.x >> BKTSH], 1);
        int p1 = atomicAdd(&cnt[d.y >> BKTSH], 1);
        int p2 = atomicAdd(&cnt[d.z >> BKTSH], 1);
        int p3 = atomicAdd(&cnt[d.w >> BKTSH], 1);
        P[p0] = ((d.x & (BKTW - 1)) << 18) | s.x;
        P[p1] = ((d.y & (BKTW - 1)) << 18) | s.y;
        P[p2] = ((d.z & (BKTW - 1)) << 18) | s.z;
        P[p3] = ((d.w & (BKTW - 1)) << 18) | s.w;
    }
}

// Phase B: one block (1024 thr) per bucket (1024 nodes) -> rp, dinv, colidx.
// Sorted colidx built in LDS, streamed out with coalesced full-line writes.
__global__ __launch_bounds__(ABLK) void k_csrB(const int* __restrict__ P,
                                               const int* __restrict__ S,
                                               int* __restrict__ rp,
                                               float* __restrict__ dinv,
                                               int* __restrict__ colidx) {
    __shared__ int outl[CAP];          // 136 KB
    __shared__ int deg[BKTW];
    __shared__ int wp[BKTW];
    __shared__ int sc[BKTW];
    __shared__ int se[2];
    int b = blockIdx.x, tid = threadIdx.x;
    if (tid == 0) {
        se[0] = S[b * NBLKA];
        se[1] = (b == NBKT - 1) ? NEDGES : S[(b + 1) * NBLKA];
    }
    deg[tid] = 0;
    __syncthreads();
    int start = se[0], end = se[1];

    // pass 1: histogram (v4i vectorized main body + scalar edges)
    {
        int a4 = (start + 3) & ~3;           // first 16B-aligned index
        int e4 = end & ~3;                   // last full int4 end
        for (int i = start + tid; i < a4 && i < end; i += ABLK)
            atomicAdd(&deg[P[i] >> 18], 1);
        const v4i* p4 = (const v4i*)(P + a4);
        int n4 = (e4 > a4) ? (e4 - a4) >> 2 : 0;
        for (int q = tid; q < n4; q += ABLK) {
            v4i v = p4[q];
            atomicAdd(&deg[v.x >> 18], 1);
            atomicAdd(&deg[v.y >> 18], 1);
            atomicAdd(&deg[v.z >> 18], 1);
            atomicAdd(&deg[v.w >> 18], 1);
        }
        for (int i = (e4 > a4 ? e4 : start) + tid; i < end; i += ABLK)
            if (i >= a4 || e4 <= a4) {}      // covered above
        for (int i = e4 + tid; i < end && e4 > a4; i += ABLK)
            atomicAdd(&deg[P[i] >> 18], 1);
    }
    __syncthreads();

    int myc = deg[tid];
    sc[tid] = myc;
    __syncthreads();
    for (int off = 1; off < BKTW; off <<= 1) {
        int v = (tid >= off) ? sc[tid - off] : 0;
        __syncthreads();
        sc[tid] += v;
        __syncthreads();
    }
    wp[tid] = start + sc[tid] - myc;    // exclusive prefix (absolute)
    int node = b * BKTW + tid;
    if (node < NNODES) {
        rp[node]   = wp[tid];
        dinv[node] = rsqrtf(1.f + (float)myc);
    }
    if (b == 0 && tid == 0) rp[NNODES] = NEDGES;
    __syncthreads();

    // pass 2: place into LDS at sorted relative position
    for (int i = start + tid; i < end; i += ABLK) {
        int v = P[i];
        int pos = atomicAdd(&wp[v >> 18], 1);
        int rel = pos - start;
        if (rel < CAP) outl[rel] = v & 0x3FFFF;
        else           colidx[pos] = v & 0x3FFFF;
    }
    __syncthreads();

    int cnt = end - start;
    if (cnt > CAP) cnt = CAP;
    for (int i = tid; i < cnt; i += ABLK)
        colidx[start + i] = outl[i];
}

// A1b[i][j] = bf16( dinv[i] * (x[i] @ W1)[j] )   (node-major, 32B rows)
#define GROWS 64
#define GPAD  129
__global__ __launch_bounds__(256) void k_gemm1(const float* __restrict__ x,
                                               const float* __restrict__ W1,
                                               const float* __restrict__ dinv,
                                               unsigned short* __restrict__ A1b) {
    __shared__ float xt[GROWS * GPAD];       // 33 KB
    __shared__ float Ws[NFEAT * NH];         // 8 KB
    int tid = threadIdx.x;
    int r0 = blockIdx.x * GROWS;

    #pragma unroll
    for (int t = 0; t < (NFEAT * NH) / 256; ++t)   // 8
        Ws[tid + t * 256] = W1[tid + t * 256];

    const float4* xg = (const float4*)(x + (size_t)r0 * NFEAT);
    #pragma unroll
    for (int t = 0; t < (GROWS * NFEAT / 4) / 256; ++t) {  // 8
        int fi = tid + t * 256;              // float4 index within tile
        float4 v = xg[fi];
        int row = fi >> 5;                   // 32 float4 per row
        int c4  = fi & 31;
        float* p = &xt[row * GPAD + c4 * 4];
        p[0] = v.x; p[1] = v.y; p[2] = v.z; p[3] = v.w;
    }
    __syncthreads();

    int r  = tid >> 2;      // 0..63
    int jq = tid & 3;       // output col quarter
    float4 acc = make_float4(0.f, 0.f, 0.f, 0.f);
    #pragma unroll 8
    for (int k = 0; k < NFEAT; ++k) {
        float xv = xt[r * GPAD + k];
        float4 w = *(const float4*)&Ws[k * NH + jq * 4];
        acc.x += xv * w.x; acc.y += xv * w.y;
        acc.z += xv * w.z; acc.w += xv * w.w;
    }
    int n = r0 + r;
    float s = dinv[n];
    ushort4 o;
    o.x = f2bf(acc.x * s); o.y = f2bf(acc.y * s);
    o.z = f2bf(acc.z * s); o.w = f2bf(acc.w * s);
    *(ushort4*)&A1b[(size_t)n * NH + jq * 4] = o;
}

// gather1: t = A1[n] + sum_nbr A1[c] (unmasked 16-batches + masked tail);
// h = relu(dinv*t + b1); A2b[n] = bf16(dinv*(h@W2)) via width-16 shuffles.
__global__ __launch_bounds__(256) void k_gather1(const unsigned short* __restrict__ A1b,
                                                 const int* __restrict__ rp,
                                                 const int* __restrict__ ci,
                                                 const float* __restrict__ dinv,
                                                 const float* __restrict__ b1,
                                                 const float* __restrict__ W2,
                                                 unsigned short* __restrict__ A2b) {
    __shared__ float W2s[NH * NH];
    __shared__ float b1s[NH];
    int tid = threadIdx.x;
    if (tid < NH * NH) W2s[tid] = W2[tid];
    if (tid < NH)      b1s[tid] = b1[tid];
    __syncthreads();

    int nl = tid >> 4, j = tid & 15;
    int n  = blockIdx.x * 16 + nl;          // 12500*16 == NNODES exactly
    int r0 = rp[n], r1 = rp[n + 1];

    float acc = bf2f(A1b[(size_t)n * NH + j]);   // self-loop term
    int k = r0;
    for (; k + 16 <= r1; k += 16) {              // full batches, no masking
        int   c[16];
        float v[16];
        #pragma unroll
        for (int u = 0; u < 16; ++u) c[u] = ci[k + u];
        #pragma unroll
        for (int u = 0; u < 16; ++u) v[u] = bf2f(A1b[(size_t)c[u] * NH + j]);
        #pragma unroll
        for (int u = 0; u < 16; ++u) acc += v[u];
    }
    if (k < r1) {                                // one masked tail batch
        int   c[16];
        float v[16];
        #pragma unroll
        for (int u = 0; u < 16; ++u) c[u] = ci[k + u];   // pad-protected
        #pragma unroll
        for (int u = 0; u < 16; ++u) v[u] = bf2f(A1b[(size_t)c[u] * NH + j]);
        #pragma unroll
        for (int u = 0; u < 16; ++u) acc += (k + u < r1) ? v[u] : 0.f;
    }

    float h = fmaxf(acc * dinv[n] + b1s[j], 0.f);
    float o = 0.f;
    #pragma unroll
    for (int kk = 0; kk < NH; ++kk)
        o += __shfl(h, kk, 16) * W2s[kk * NH + j];
    A2b[(size_t)n * NH + j] = f2bf(o * dinv[n]);
}

// gather2: t = A2[n] + sum_nbr A2[c]; h2 = dinv*t + b2; G[batch[n]] += h2
__global__ __launch_bounds__(256) void k_gather2(const unsigned short* __restrict__ A2b,
                                                 const int* __restrict__ rp,
                                                 const int* __restrict__ ci,
                                                 const float* __restrict__ dinv,
                                                 const float* __restrict__ b2,
                                                 const int* __restrict__ batch,
                                                 float* __restrict__ G) {
    __shared__ float b2s[NH];
    int tid = threadIdx.x;
    if (tid < NH) b2s[tid] = b2[tid];
    __syncthreads();

    int nl = tid >> 4, j = tid & 15;
    int n  = blockIdx.x * 16 + nl;
    int r0 = rp[n], r1 = rp[n + 1];

    float acc = bf2f(A2b[(size_t)n * NH + j]);
    int k = r0;
    for (; k + 16 <= r1; k += 16) {
        int   c[16];
        float v[16];
        #pragma unroll
        for (int u = 0; u < 16; ++u) c[u] = ci[k + u];
        #pragma unroll
        for (int u = 0; u < 16; ++u) v[u] = bf2f(A2b[(size_t)c[u] * NH + j]);
        #pragma unroll
        for (int u = 0; u < 16; ++u) acc += v[u];
    }
    if (k < r1) {
        int   c[16];
        float v[16];
        #pragma unroll
        for (int u = 0; u < 16; ++u) c[u] = ci[k + u];
        #pragma unroll
        for (int u = 0; u < 16; ++u) v[u] = bf2f(A2b[(size_t)c[u] * NH + j]);
        #pragma unroll
        for (int u = 0; u < 16; ++u) acc += (k + u < r1) ? v[u] : 0.f;
    }

    float h2 = acc * dinv[n] + b2s[j];
    atomicAdd(&G[(size_t)batch[n] * NH + j], h2);
}

// head: per graph: relu(G) -> MLP1 -> relu -> MLP2 -> out
__global__ __launch_bounds__(128) void k_head(const float* __restrict__ G,
                                              const float* __restrict__ Wl1,
                                              const float* __restrict__ bl1,
                                              const float* __restrict__ Wl2,
                                              const float* __restrict__ bl2,
                                              float* __restrict__ out) {
    __shared__ float gv[NH];
    __shared__ float g1[NMLP];
    int g = blockIdx.x, tid = threadIdx.x;

    if (tid < NH) gv[tid] = fmaxf(G[(size_t)g * NH + tid], 0.f);
    __syncthreads();

    if (tid < NMLP) {
        float a = bl1[tid];
        #pragma unroll
        for (int k = 0; k < NH; ++k) a += gv[k] * Wl1[k * NMLP + tid];
        g1[tid] = fmaxf(a, 0.f);
    }
    __syncthreads();

    if (tid < NCLS) {
        float a = bl2[tid];
        for (int k = 0; k < NMLP; ++k) a += g1[k] * Wl2[k * NCLS + tid];
        out[(size_t)g * NCLS + tid] = a;
    }
}

// ---------------------------------------------------------------------------
extern "C" void kernel_launch(void* const* d_in, const int* in_sizes, int n_in,
                              void* d_out, int out_size, void* d_ws, size_t ws_size,
                              hipStream_t stream) {
    const float* x     = (const float*)d_in[0];
    const int*   edge  = (const int*)d_in[1];   // [2, E] flat: src then dst
    const int*   batch = (const int*)d_in[2];
    const float* W1    = (const float*)d_in[3];
    const float* b1    = (const float*)d_in[4];
    const float* W2    = (const float*)d_in[5];
    const float* b2    = (const float*)d_in[6];
    const float* Wl1   = (const float*)d_in[7];
    const float* bl1   = (const float*)d_in[8];
    const float* Wl2   = (const float*)d_in[9];
    const float* bl2   = (const float*)d_in[10];
    float*       out   = (float*)d_out;

    // workspace layout (256B aligned)
    char* ws = (char*)d_ws;
    size_t cur = 0;
    auto alloc = [&](size_t bytes) {
        void* p = ws + cur;
        cur += (bytes + 255) & ~(size_t)255;
        return p;
    };
    int*   H      = (int*)  alloc((size_t)HSZ * 4);            // 401 KB (becomes S)
    int*   bsum   = (int*)  alloc((size_t)NSCAN2 * 4);
    int*   P      = (int*)  alloc((size_t)NEDGES * 4);         // 25.6 MB packed pairs
    int*   colidx = (int*)  alloc((size_t)(NEDGES + 64) * 4);  // + 64-int zero pad
    int*   rp     = (int*)  alloc((size_t)(NNODES + 1) * 4);
    float* dinv   = (float*)alloc((size_t)NNODES * 4);
    float* G      = (float*)alloc((size_t)NGRAPH * NH * 4);
    // bf16 tables alias P (dead after k_csrB): 2 x 6.4 MB
    unsigned short* A1b = (unsigned short*)P;
    unsigned short* A2b = A1b + (size_t)NNODES * NH;

    const int* src = edge;
    const int* dst = edge + NEDGES;

    int nb_gemm = NNODES / GROWS;                     // 3125
    int nb_gath = NNODES / 16;                        // 12500

    k_histA     <<<NBLKA,  ABLK, 0, stream>>>(dst, H);
    k_scan_part <<<NSCAN2, 256, 0, stream>>>(H, bsum);
    k_scan_top  <<<1,      256, 0, stream>>>(bsum, G, colidx + NEDGES);
    k_scan_final<<<NSCAN2, 256, 0, stream>>>(H, bsum);
    k_scatterA  <<<NBLKA,  ABLK, 0, stream>>>(src, dst, H, P);
    k_csrB      <<<NBKT,   ABLK, 0, stream>>>(P, H, rp, dinv, colidx);
    k_gemm1     <<<nb_gemm, 256, 0, stream>>>(x, W1, dinv, A1b);
    k_gather1   <<<nb_gath, 256, 0, stream>>>(A1b, rp, colidx, dinv, b1, W2, A2b);
    k_gather2   <<<nb_gath, 256, 0, stream>>>(A2b, rp, colidx, dinv, b2, batch, G);
    k_head      <<<NGRAPH, 128, 0, stream>>>(G, Wl1, bl1, Wl2, bl2, out);
}